// Round 3
// baseline (2155.582 us; speedup 1.0000x reference)
//
#include <hip/hip_runtime.h>
#include <hip/hip_cooperative_groups.h>

namespace cg = cooperative_groups;

// FirUpsample = fused transposed-conv(3x3, stride-2) + 4x4 FIR, recast as GEMM:
//   D[m][col] = sum_k A[m][k] * B[k][col]
//   m = oc*4 + par (1024), col = (n,a,b) (16384), k = tap*256 + ic (2304)
//   A = W_eff composites (phase 1 -> d_ws, bf16), B = im2col(x) staged in LDS.
// Single cooperative kernel: compose -> grid.sync (agent fences) -> GEMM.
// This avoids the cross-kernel d_ws handoff that diverged under graph replay
// (per-XCD L2 staleness across graph-node boundaries).

typedef short bf16x8 __attribute__((ext_vector_type(8)));
typedef float f32x16 __attribute__((ext_vector_type(16)));
typedef float f32x2 __attribute__((ext_vector_type(2)));

#define WEFF_BYTES (1024ull * 9 * 256 * 2)

static __device__ __forceinline__ short f2bf(float f) {
  union { float f; unsigned u; } v; v.f = f;
  unsigned r = (v.u + 0x7FFFu + ((v.u >> 16) & 1u)) >> 16;
  return (short)r;
}

__global__ __launch_bounds__(256, 2)
void fir_up_coop(const float* __restrict__ x, const float* __restrict__ w,
                 short* __restrict__ Wg, float* __restrict__ out) {
  const int tid = threadIdx.x;

  // ---------------- phase 1: compose W_eff for m = blockIdx.x*2 + {0,1} ----------------
  {
    const int ic = tid;
    const float kf[4] = {0.25f, 0.75f, 0.75f, 0.25f};
#pragma unroll
    for (int mm = 0; mm < 2; ++mm) {
      const int m = blockIdx.x * 2 + mm;
      const int oc = m >> 2, par = m & 3;
      const int ry = par >> 1, rx = par & 1;
      float cy[3][3], cx[3][3];
#pragma unroll
      for (int j = 0; j < 3; ++j)
#pragma unroll
        for (int kq = 0; kq < 3; ++kq) {
          const int my = 2 * j + 1 - ry - kq;
          cy[j][kq] = (my < 0 || my > 3) ? 0.f : kf[my];
          const int mx = 2 * j + 1 - rx - kq;
          cx[j][kq] = (mx < 0 || mx > 3) ? 0.f : kf[mx];
        }
      const float* wp = w + ((size_t)oc * 256 + ic) * 9;
      float wv[9];
#pragma unroll
      for (int u = 0; u < 9; ++u) wv[u] = wp[u];
      float tmp[3][3];
#pragma unroll
      for (int ky = 0; ky < 3; ++ky)
#pragma unroll
        for (int i = 0; i < 3; ++i)
          tmp[ky][i] = wv[3*ky+0]*cx[i][0] + wv[3*ky+1]*cx[i][1] + wv[3*ky+2]*cx[i][2];
#pragma unroll
      for (int j = 0; j < 3; ++j)
#pragma unroll
        for (int i = 0; i < 3; ++i) {
          const float val = cy[j][0]*tmp[0][i] + cy[j][1]*tmp[1][i] + cy[j][2]*tmp[2][i];
          Wg[((size_t)m * 9 + (j * 3 + i)) * 256 + ic] = f2bf(val);
        }
    }
  }

  __threadfence();          // release: push Wg writes to agent coherence point
  cg::this_grid().sync();   // all blocks' phase-1 complete
  __threadfence();          // acquire: invalidate stale cached Wg lines

  // ---------------- phase 2: GEMM ----------------
  // XCD swizzle over 512 blocks: each XCD owns one mtile (A-panel L2-resident)
  const int orig = blockIdx.x;
  const int wg = (orig & 7) * 64 + (orig >> 3);
  const int mtile = wg >> 6;          // 0..7
  const int pair = wg & 63;           // 2 n-tiles per block

  const int lane = tid & 63;
  const int wid = tid >> 6;
  const int waveM = wid >> 1, waveN = wid & 1;
  const int l31 = lane & 31, q = lane >> 5;

  __shared__ short xs[180 * 32];  // [cell=h*18+w][32 ic; slot XOR (cell&3) swizzle]

  // A lane base pointers: row m = mtile*128 + waveM*64 + mf*32 + l31
  const short* pA[2];
#pragma unroll
  for (int mf = 0; mf < 2; ++mf) {
    const int mrow = mtile * 128 + waveM * 64 + mf * 32 + l31;
    pA[mf] = Wg + (size_t)mrow * (9 * 256) + q * 8;
  }
  // B lane base cell (per nf)
  int cellB[2];
#pragma unroll
  for (int nf = 0; nf < 2; ++nf) {
    const int c = waveN * 64 + nf * 32 + l31;
    cellB[nf] = (c >> 4) * 18 + (c & 15);   // ay*18 + bx
  }

  for (int rep = 0; rep < 2; ++rep) {
    const int ntile = pair * 2 + rep;
    const int n = ntile >> 5;
    const int atile = (ntile >> 2) & 7;
    const int btile = ntile & 3;
    const int a0 = atile * 8, b0 = btile * 16;

    f32x16 acc[2][2];
#pragma unroll
    for (int mf = 0; mf < 2; ++mf)
#pragma unroll
      for (int nf = 0; nf < 2; ++nf)
#pragma unroll
        for (int e = 0; e < 16; ++e) acc[mf][nf][e] = 0.f;

    for (int cc = 0; cc < 8; ++cc) {
      __syncthreads();  // previous reads (or previous rep) done before overwrite
      for (int u = tid; u < 720; u += 256) {
        const int cell = u >> 2, slot = u & 3;
        const int hh = cell / 18;
        const int ww = cell - hh * 18;
        const int gh = a0 - 1 + hh, gw = b0 - 1 + ww;
        const bool ok = (gh >= 0) & (gh < 64) & (gw >= 0) & (gw < 64);
        const float* xp = x + (((size_t)(n * 256 + cc * 32 + slot * 8)) * 64 + gh) * 64 + gw;
        bf16x8 vv;
#pragma unroll
        for (int e = 0; e < 8; ++e) {
          const float f = ok ? xp[(size_t)e * 4096] : 0.f;
          vv[e] = f2bf(f);
        }
        *(bf16x8*)(xs + cell * 32 + ((slot ^ (cell & 3)) * 8)) = vv;
      }
      __syncthreads();

      const short* a0p = pA[0] + cc * 32;
      const short* a1p = pA[1] + cc * 32;
#pragma unroll
      for (int s = 0; s < 2; ++s) {
        const int s2q = 2 * s + q;
#pragma unroll
        for (int t = 0; t < 9; ++t) {
          const int j = t / 3, i = t % 3;
          const bf16x8 A0 = *(const bf16x8*)(a0p + t * 256 + s * 16);
          const bf16x8 A1 = *(const bf16x8*)(a1p + t * 256 + s * 16);
          const int ct0 = cellB[0] + j * 18 + i;
          const int ct1 = cellB[1] + j * 18 + i;
          const bf16x8 B0 = *(const bf16x8*)(xs + ct0 * 32 + ((s2q ^ (ct0 & 3)) * 8));
          const bf16x8 B1 = *(const bf16x8*)(xs + ct1 * 32 + ((s2q ^ (ct1 & 3)) * 8));
          acc[0][0] = __builtin_amdgcn_mfma_f32_32x32x16_bf16(A0, B0, acc[0][0], 0, 0, 0);
          acc[0][1] = __builtin_amdgcn_mfma_f32_32x32x16_bf16(A0, B1, acc[0][1], 0, 0, 0);
          acc[1][0] = __builtin_amdgcn_mfma_f32_32x32x16_bf16(A1, B0, acc[1][0], 0, 0, 0);
          acc[1][1] = __builtin_amdgcn_mfma_f32_32x32x16_bf16(A1, B1, acc[1][1], 0, 0, 0);
        }
      }
    }

    // epilogue: 16 regs/lane = 4 ocs x 4 parities -> dense 2x2 output quads
#pragma unroll
    for (int mf = 0; mf < 2; ++mf)
#pragma unroll
      for (int nf = 0; nf < 2; ++nf) {
        const int c = waveN * 64 + nf * 32 + l31;
        const int ay = c >> 4, bxv = c & 15;
        const int arow = a0 + ay, bcol = b0 + bxv;
        const int ocb2 = mtile * 32 + waveM * 16 + mf * 8 + q;
#pragma unroll
        for (int r2 = 0; r2 < 4; ++r2) {
          const int oc = ocb2 + 2 * r2;
          float* op = out + (((size_t)(n * 256 + oc)) * 128 + 2 * arow) * 128 + 2 * bcol;
          f32x2 v0, v1;
          v0[0] = acc[mf][nf][4*r2+0]; v0[1] = acc[mf][nf][4*r2+1];  // row 2a
          v1[0] = acc[mf][nf][4*r2+2]; v1[1] = acc[mf][nf][4*r2+3];  // row 2a+1
          *(f32x2*)op = v0;
          *(f32x2*)(op + 128) = v1;
        }
      }
  }
}

// ---------------- fallback: verified fp32 kernel (ws too small / coop launch fails) ----------------
#define XIC 256
#define XOC 256
#define XH 64
#define XW 64
#define OHW 128
constexpr int OCT  = 16;
constexpr int ICCH = 32;

__device__ __forceinline__ void load_row(const float* __restrict__ xrow,
                                         bool rowok, bool cL, bool cR, int b0,
                                         float r[10]) {
  if (rowok) {
    r[0] = cL ? xrow[b0 - 1] : 0.f;
#pragma unroll
    for (int c = 1; c < 9; ++c) r[c] = xrow[b0 - 1 + c];
    r[9] = cR ? xrow[b0 + 8] : 0.f;
  } else {
#pragma unroll
    for (int c = 0; c < 10; ++c) r[c] = 0.f;
  }
}

__global__ __launch_bounds__(256)
void fir_up_fused(const float* __restrict__ x, const float* __restrict__ w,
                  float* __restrict__ out) {
  const int bid   = blockIdx.x;
  const int stile = bid & 3;
  const int oct   = (bid >> 2) & 15;
  const int n     = (bid >> 6) & 3;
  const int par   = (bid >> 8) & 3;
  const int ry = par >> 1, rx = par & 1;
  const int a0b = (stile >> 1) * 32;
  const int b0b = (stile & 1) * 32;
  const int tid = threadIdx.x;
  const int ocx = tid & 15;
  const int sp  = tid >> 4;
  const int spy = sp >> 2, spx = sp & 3;
  const int a0 = a0b + spy * 8;
  const int b0 = b0b + spx * 8;
  __shared__ float Wp[ICCH][OCT][10];
  float cy[3][3], cx[3][3];
#pragma unroll
  for (int j = 0; j < 3; ++j)
#pragma unroll
    for (int kq = 0; kq < 3; ++kq) {
      const int my = 2 * j + 1 - ry - kq;
      cy[j][kq] = (my < 0 || my > 3) ? 0.f : ((my == 1 || my == 2) ? 0.75f : 0.25f);
      const int mx = 2 * j + 1 - rx - kq;
      cx[j][kq] = (mx < 0 || mx > 3) ? 0.f : ((mx == 1 || mx == 2) ? 0.75f : 0.25f);
    }
  const bool cL = (b0 > 0);
  const bool cR = (b0 + 8 < XW);
  float acc[8][8];
#pragma unroll
  for (int i = 0; i < 8; ++i)
#pragma unroll
    for (int j = 0; j < 8; ++j) acc[i][j] = 0.f;
  for (int icc = 0; icc < XIC; icc += ICCH) {
    __syncthreads();
#pragma unroll
    for (int t = 0; t < 2; ++t) {
      const int qq   = tid + t * 256;
      const int ic_l = qq >> 4;
      const int oc_l = qq & 15;
      const float* wp = w + ((size_t)(oct * OCT + oc_l) * XIC + (icc + ic_l)) * 9;
      float wv[9];
#pragma unroll
      for (int u = 0; u < 9; ++u) wv[u] = wp[u];
      float tmp[3][3];
#pragma unroll
      for (int ky = 0; ky < 3; ++ky)
#pragma unroll
        for (int i = 0; i < 3; ++i)
          tmp[ky][i] = wv[3*ky+0]*cx[i][0] + wv[3*ky+1]*cx[i][1] + wv[3*ky+2]*cx[i][2];
#pragma unroll
      for (int j = 0; j < 3; ++j)
#pragma unroll
        for (int i = 0; i < 3; ++i)
          Wp[ic_l][oc_l][3*j+i] =
              cy[j][0]*tmp[0][i] + cy[j][1]*tmp[1][i] + cy[j][2]*tmp[2][i];
    }
    __syncthreads();
    for (int il = 0; il < ICCH; ++il) {
      const int ic = icc + il;
      const float* xpl = x + ((size_t)(n * XIC + ic) * XH) * XW;
      float wv[9];
#pragma unroll
      for (int u = 0; u < 9; ++u) wv[u] = Wp[il][ocx][u];
      float rows[3][10];
      load_row(xpl + (a0 - 1) * XW, a0 >= 1, cL, cR, b0, rows[0]);
      load_row(xpl + a0 * XW, true, cL, cR, b0, rows[1]);
#pragma unroll
      for (int dy = 0; dy < 8; ++dy) {
        const int iy = a0 + dy + 1;
        load_row(xpl + iy * XW, iy < XH, cL, cR, b0, rows[(dy + 2) % 3]);
#pragma unroll
        for (int dx = 0; dx < 8; ++dx) {
          float s = acc[dy][dx];
          s += wv[0]*rows[dy%3][dx] + wv[1]*rows[dy%3][dx+1] + wv[2]*rows[dy%3][dx+2];
          s += wv[3]*rows[(dy+1)%3][dx] + wv[4]*rows[(dy+1)%3][dx+1] + wv[5]*rows[(dy+1)%3][dx+2];
          s += wv[6]*rows[(dy+2)%3][dx] + wv[7]*rows[(dy+2)%3][dx+1] + wv[8]*rows[(dy+2)%3][dx+2];
          acc[dy][dx] = s;
        }
      }
    }
  }
  const int oc = oct * OCT + ocx;
  float* op = out + ((size_t)n * XOC + oc) * OHW * OHW;
#pragma unroll
  for (int dy = 0; dy < 8; ++dy) {
    const int oy = 2 * (a0 + dy) + ry;
#pragma unroll
    for (int dx = 0; dx < 8; ++dx) {
      const int ox = 2 * (b0 + dx) + rx;
      op[oy * OHW + ox] = acc[dy][dx];
    }
  }
}

extern "C" void kernel_launch(void* const* d_in, const int* in_sizes, int n_in,
                              void* d_out, int out_size, void* d_ws, size_t ws_size,
                              hipStream_t stream) {
  (void)in_sizes; (void)n_in; (void)out_size;
  const float* x = (const float*)d_in[0];
  const float* w = (const float*)d_in[1];
  float* out = (float*)d_out;
  bool ok = false;
  if (ws_size >= WEFF_BYTES) {
    short* Wg = (short*)d_ws;
    void* args[4] = {(void*)&x, (void*)&w, (void*)&Wg, (void*)&out};
    hipError_t e = hipLaunchCooperativeKernel((const void*)fir_up_coop,
                                              dim3(512), dim3(256), args, 0, stream);
    ok = (e == hipSuccess);
  }
  if (!ok) {
    hipLaunchKernelGGL(fir_up_fused, dim3(1024), dim3(256), 0, stream, x, w, out);
  }
}

// Round 4
// 135.502 us; speedup vs baseline: 15.9081x; 15.9081x over previous
//
#include <hip/hip_runtime.h>

// FirUpsample = fused transposed-conv(3x3, stride-2) + 4x4 FIR, as one implicit GEMM:
//   D[m][col] = sum_k A[m][k] * B[k][col]
//   m = oc*4 + par (1024), col = (n,a,b) (16384), k = (tap, ic) (9*256)
//   A = W_eff composites, composed PER BLOCK per K-chunk into LDS (no global
//   intermediate -> no cross-kernel coherence hazard, graph-capture safe).
//   B = im2col(x) staged in LDS (bf16, slot-XOR swizzle).
// out[n][oc][2a+ry][2b+rx], (ry,rx) = par bits. Verified layout math from R1.

typedef short bf16x4 __attribute__((ext_vector_type(4)));
typedef short bf16x8 __attribute__((ext_vector_type(8)));
typedef float f32x16 __attribute__((ext_vector_type(16)));
typedef float f32x2 __attribute__((ext_vector_type(2)));

static __device__ __forceinline__ short f2bf(float f) {
  union { float f; unsigned u; } v; v.f = f;
  unsigned r = (v.u + 0x7FFFu + ((v.u >> 16) & 1u)) >> 16;
  return (short)r;
}

// Tiles: M=64 (16 oc x 4 par), N=256 cols (8 a-rows x 32 b-cols), K-chunk = 32 ic.
// 4 waves, each 64m x 64n (acc[2][2] of 32x32 frags).
__global__ __launch_bounds__(256, 2)
void fir_up_onepass(const float* __restrict__ x, const float* __restrict__ w,
                    float* __restrict__ out) {
  // XCD-contiguous ntile grouping: xcd = bid&7 owns ntiles xcd*8..xcd*8+7
  const int bid = blockIdx.x;
  const int wg = (bid & 7) * 128 + (bid >> 3);
  const int mtile = wg & 15;         // 0..15 (16 ocs each)
  const int ntile = wg >> 4;         // 0..63
  const int n = ntile >> 4;
  const int atile = (ntile >> 1) & 7;
  const int btile = ntile & 1;
  const int a0 = atile * 8, b0 = btile * 32;

  const int tid = threadIdx.x;
  const int lane = tid & 63;
  const int wid = tid >> 6;
  const int l31 = lane & 31, q = lane >> 5;

  __shared__ short AsS[64 * 9 * 32];   // 36864 B, XOR ((m&7)<<4) swizzle
  __shared__ short xsS[340 * 32];      // 21760 B, slot^(cell&3) swizzle
  char* Ab = (char*)AsS;
  short* xs = xsS;

  // ---- compose constants (per thread: fixed parity) ----
  const int mloc = tid & 63;           // m_local this thread composes
  const int ic8 = tid >> 6;            // which 8-ic slot (0..3)
  const int parC = mloc & 3;
  const int ocC = mtile * 16 + (mloc >> 2);
  const int swzC = (mloc & 7) << 4;
  const float kf[4] = {0.25f, 0.75f, 0.75f, 0.25f};
  float cy[3][3], cx[3][3];
  {
    const int ry = parC >> 1, rx = parC & 1;
#pragma unroll
    for (int j = 0; j < 3; ++j)
#pragma unroll
      for (int kq = 0; kq < 3; ++kq) {
        const int my = 2 * j + 1 - ry - kq;
        cy[j][kq] = (my < 0 || my > 3) ? 0.f : kf[my];
        const int mx = 2 * j + 1 - rx - kq;
        cx[j][kq] = (mx < 0 || mx > 3) ? 0.f : kf[mx];
      }
  }

  f32x16 acc[2][2];
#pragma unroll
  for (int mf = 0; mf < 2; ++mf)
#pragma unroll
    for (int nf = 0; nf < 2; ++nf)
#pragma unroll
      for (int e = 0; e < 16; ++e) acc[mf][nf][e] = 0.f;

  // A-fragment read bases (byte offsets into As, pre-XOR applied per lane)
  const int swzA = (l31 & 7) << 4;
  int rawA[2];
#pragma unroll
  for (int mf = 0; mf < 2; ++mf) rawA[mf] = (mf * 32 + l31) * 576 + q * 16;

  // B-fragment base cells: col c = (ay,bx), ay = 2*wid+nf, bx = l31
  int cellB[2];
#pragma unroll
  for (int nf = 0; nf < 2; ++nf) cellB[nf] = (2 * wid + nf) * 34 + l31;

  for (int cc = 0; cc < 8; ++cc) {
    __syncthreads();  // previous chunk's LDS reads complete

    // ---- stage x chunk: 340 cells x 32 ic, fp32 -> bf16 ----
    for (int u = tid; u < 1360; u += 256) {
      const int cell = u >> 2, slot = u & 3;
      const int hh = cell / 34;
      const int ww = cell - hh * 34;
      const int gh = a0 - 1 + hh, gw = b0 - 1 + ww;
      const bool ok = (gh >= 0) & (gh < 64) & (gw >= 0) & (gw < 64);
      const float* xp = x + (((size_t)(n * 256 + cc * 32 + slot * 8)) * 64 + gh) * 64 + gw;
      bf16x8 vv;
#pragma unroll
      for (int e = 0; e < 8; ++e) {
        const float f = ok ? xp[(size_t)e * 4096] : 0.f;
        vv[e] = f2bf(f);
      }
      *(bf16x8*)(xs + cell * 32 + ((slot ^ (cell & 3)) * 8)) = vv;
    }

    // ---- compose A chunk: As[m][t][ic], this thread owns (mloc, ic8), 2 groups of 4 ic ----
#pragma unroll
    for (int g = 0; g < 2; ++g) {
      const int icg = cc * 32 + ic8 * 8 + g * 4;
      const float* wp = w + ((size_t)ocC * 256 + icg) * 9;
      float sval[9][4];
#pragma unroll
      for (int v = 0; v < 4; ++v) {
        float wv[9];
#pragma unroll
        for (int u = 0; u < 9; ++u) wv[u] = wp[v * 9 + u];
        float tmp[3][3];
#pragma unroll
        for (int ky = 0; ky < 3; ++ky)
#pragma unroll
          for (int i = 0; i < 3; ++i)
            tmp[ky][i] = wv[3*ky+0]*cx[i][0] + wv[3*ky+1]*cx[i][1] + wv[3*ky+2]*cx[i][2];
#pragma unroll
        for (int j = 0; j < 3; ++j)
#pragma unroll
          for (int i = 0; i < 3; ++i)
            sval[j*3+i][v] = cy[j][0]*tmp[0][i] + cy[j][1]*tmp[1][i] + cy[j][2]*tmp[2][i];
      }
#pragma unroll
      for (int t = 0; t < 9; ++t) {
        bf16x4 pk;
#pragma unroll
        for (int v = 0; v < 4; ++v) pk[v] = f2bf(sval[t][v]);
        const int byteoff = mloc * 576 + t * 64 + ic8 * 16 + g * 8;
        *(bf16x4*)(Ab + (byteoff ^ swzC)) = pk;
      }
    }
    __syncthreads();

    // ---- MFMA: k = (s half of 32 ic) x (9 taps) ----
#pragma unroll
    for (int s = 0; s < 2; ++s) {
      const int s2q = 2 * s + q;
#pragma unroll
      for (int t = 0; t < 9; ++t) {
        const int j = t / 3, i = t % 3;
        const int aoff = t * 64 + s * 32;
        const bf16x8 A0 = *(const bf16x8*)(Ab + ((rawA[0] + aoff) ^ swzA));
        const bf16x8 A1 = *(const bf16x8*)(Ab + ((rawA[1] + aoff) ^ swzA));
        const int ct0 = cellB[0] + j * 34 + i;
        const int ct1 = cellB[1] + j * 34 + i;
        const bf16x8 B0 = *(const bf16x8*)(xs + ct0 * 32 + ((s2q ^ (ct0 & 3)) * 8));
        const bf16x8 B1 = *(const bf16x8*)(xs + ct1 * 32 + ((s2q ^ (ct1 & 3)) * 8));
        acc[0][0] = __builtin_amdgcn_mfma_f32_32x32x16_bf16(A0, B0, acc[0][0], 0, 0, 0);
        acc[0][1] = __builtin_amdgcn_mfma_f32_32x32x16_bf16(A0, B1, acc[0][1], 0, 0, 0);
        acc[1][0] = __builtin_amdgcn_mfma_f32_32x32x16_bf16(A1, B0, acc[1][0], 0, 0, 0);
        acc[1][1] = __builtin_amdgcn_mfma_f32_32x32x16_bf16(A1, B1, acc[1][1], 0, 0, 0);
      }
    }
  }

  // ---- epilogue: regs = 4 oc x 4 parities -> dense 2x2 output quads ----
#pragma unroll
  for (int mf = 0; mf < 2; ++mf)
#pragma unroll
    for (int nf = 0; nf < 2; ++nf) {
      const int ay = 2 * wid + nf, bx = l31;
      const int arow = a0 + ay, bcol = b0 + bx;
#pragma unroll
      for (int r2 = 0; r2 < 4; ++r2) {
        const int oc = mtile * 16 + mf * 8 + q + 2 * r2;
        float* op = out + (((size_t)(n * 256 + oc)) * 128 + 2 * arow) * 128 + 2 * bcol;
        f32x2 v0, v1;
        v0[0] = acc[mf][nf][4*r2+0]; v0[1] = acc[mf][nf][4*r2+1];  // row 2a, (rx=0,1)
        v1[0] = acc[mf][nf][4*r2+2]; v1[1] = acc[mf][nf][4*r2+3];  // row 2a+1
        *(f32x2*)op = v0;
        *(f32x2*)(op + 128) = v1;
      }
    }
}

extern "C" void kernel_launch(void* const* d_in, const int* in_sizes, int n_in,
                              void* d_out, int out_size, void* d_ws, size_t ws_size,
                              hipStream_t stream) {
  (void)in_sizes; (void)n_in; (void)out_size; (void)d_ws; (void)ws_size;
  const float* x = (const float*)d_in[0];
  const float* w = (const float*)d_in[1];
  float* out = (float*)d_out;
  hipLaunchKernelGGL(fir_up_onepass, dim3(1024), dim3(256), 0, stream, x, w, out);
}

// Round 5
// 114.233 us; speedup vs baseline: 18.8700x; 1.1862x over previous
//
#include <hip/hip_runtime.h>

// FirUpsample = fused transposed-conv(3x3, stride-2) + 4x4 FIR, as one implicit GEMM:
//   D[m][col] = sum_k A[m][k] * B[k][col]
//   m = oc*4 + par (1024), col = (n,a,b) (16384), k = (tap, ic) (9*256)
//   A composed per block per K-chunk into LDS (graph-safe, no global intermediate),
//   B = im2col(x) staged in LDS as bf16.
// R4: BM=128/BN=256/Kc=16, conflict-free LDS layouts, float4 w-loads,
//     wave tile 64x128 (acc[2][4], 0.75 LDS reads per MFMA).

typedef float float4v __attribute__((ext_vector_type(4)));
typedef short bf16x4 __attribute__((ext_vector_type(4)));
typedef short bf16x8 __attribute__((ext_vector_type(8)));
typedef float f32x16 __attribute__((ext_vector_type(16)));
typedef float f32x2 __attribute__((ext_vector_type(2)));

static __device__ __forceinline__ short f2bf(float f) {
  union { float f; unsigned u; } v; v.f = f;
  unsigned r = (v.u + 0x7FFFu + ((v.u >> 16) & 1u)) >> 16;
  return (short)r;
}

__global__ __launch_bounds__(256, 2)
void fir_up_v4(const float* __restrict__ x, const float* __restrict__ w,
               float* __restrict__ out) {
  // XCD swizzle: xcd = bid&7 owns ntiles [xcd*8, xcd*8+8) -> x slice + w L2-resident
  const int bid = blockIdx.x;
  const int wg = (bid & 7) * 64 + (bid >> 3);
  const int ntile = wg >> 3;          // 0..63
  const int mtile = wg & 7;           // 0..7 (32 ocs x 4 par = 128 m-rows)
  const int n = ntile >> 4;
  const int atile = (ntile >> 1) & 7;
  const int btile = ntile & 1;
  const int a0 = atile * 8, b0 = btile * 32;

  const int tid = threadIdx.x;
  const int lane = tid & 63;
  const int wid = tid >> 6;
  const int waveM = wid >> 1, waveN = wid & 1;
  const int l31 = lane & 31, q = lane >> 5;

  __shared__ short AsS[128 * 9 * 16];  // 36864 B: [m][tap][16 ic], XOR ((m>>2)&1)<<4
  __shared__ short xsS[340 * 16];      // 10880 B: [cell=hh*34+ww][16 ic] (conflict-free)
  char* Ab = (char*)AsS;
  short* xs = xsS;

  // ---- compose constants: this thread owns (mloc, ich = 8-ic half) ----
  const int mloc = tid & 127;
  const int ich = tid >> 7;
  const int parC = mloc & 3;
  const int ocC = mtile * 32 + (mloc >> 2);
  const int swzC = ((mloc >> 2) & 1) << 4;
  const float kf[4] = {0.25f, 0.75f, 0.75f, 0.25f};
  float cy[3][3], cx[3][3];
  {
    const int ry = parC >> 1, rx = parC & 1;
#pragma unroll
    for (int j = 0; j < 3; ++j)
#pragma unroll
      for (int kq = 0; kq < 3; ++kq) {
        const int my = 2 * j + 1 - ry - kq;
        cy[j][kq] = (my < 0 || my > 3) ? 0.f : kf[my];
        const int mx = 2 * j + 1 - rx - kq;
        cx[j][kq] = (mx < 0 || mx > 3) ? 0.f : kf[mx];
      }
  }

  f32x16 acc[2][4];
#pragma unroll
  for (int mf = 0; mf < 2; ++mf)
#pragma unroll
    for (int nf = 0; nf < 4; ++nf)
#pragma unroll
      for (int e = 0; e < 16; ++e) acc[mf][nf][e] = 0.f;

  // A-read bases: row m_local = waveM*64 + mf*32 + l31, byte = m*288 + t*32 + q*16
  int rawA[2], swzA[2];
#pragma unroll
  for (int mf = 0; mf < 2; ++mf) {
    const int ml = waveM * 64 + mf * 32 + l31;
    rawA[mf] = ml * 288 + q * 16;
    swzA[mf] = ((ml >> 2) & 1) << 4;
  }
  // B base cells: col c = waveN*128 + nf*32 + l31 -> (ay = c>>5, bx = c&31)
  int cellB[4];
#pragma unroll
  for (int nf = 0; nf < 4; ++nf) {
    const int c = waveN * 128 + nf * 32 + l31;
    cellB[nf] = (c >> 5) * 34 + (c & 31);
  }

  for (int cc = 0; cc < 16; ++cc) {
    __syncthreads();  // previous chunk's LDS reads complete

    // ---- stage x chunk: 340 cells x 16 ic (2 slots of 8) ----
    for (int u = tid; u < 680; u += 256) {
      const int cell = u >> 1, slot = u & 1;
      const int hh = cell / 34;
      const int ww = cell - hh * 34;
      const int gh = a0 - 1 + hh, gw = b0 - 1 + ww;
      const bool ok = (gh >= 0) & (gh < 64) & (gw >= 0) & (gw < 64);
      const float* xp = x + (((size_t)(n * 256 + cc * 16 + slot * 8)) * 64 + gh) * 64 + gw;
      bf16x8 vv;
#pragma unroll
      for (int e = 0; e < 8; ++e) {
        const float f = ok ? xp[(size_t)e * 4096] : 0.f;
        vv[e] = f2bf(f);
      }
      *(bf16x8*)(xs + cell * 16 + slot * 8) = vv;
    }

    // ---- compose A chunk: As[m][t][16ic]; thread owns (mloc, ich), 2 groups of 4 ic ----
#pragma unroll
    for (int g = 0; g < 2; ++g) {
      const int icg = cc * 16 + ich * 8 + g * 4;
      const float* wp = w + ((size_t)ocC * 256 + icg) * 9;  // 36 consecutive floats, 16B-aligned
      float wv36[36];
#pragma unroll
      for (int f4 = 0; f4 < 9; ++f4)
        *(float4v*)&wv36[f4 * 4] = *(const float4v*)(wp + f4 * 4);
      float sval[9][4];
#pragma unroll
      for (int v = 0; v < 4; ++v) {
        float tmp[3][3];
#pragma unroll
        for (int ky = 0; ky < 3; ++ky)
#pragma unroll
          for (int i = 0; i < 3; ++i)
            tmp[ky][i] = wv36[v*9+3*ky+0]*cx[i][0] + wv36[v*9+3*ky+1]*cx[i][1] + wv36[v*9+3*ky+2]*cx[i][2];
#pragma unroll
        for (int j = 0; j < 3; ++j)
#pragma unroll
          for (int i = 0; i < 3; ++i)
            sval[j*3+i][v] = cy[j][0]*tmp[0][i] + cy[j][1]*tmp[1][i] + cy[j][2]*tmp[2][i];
      }
#pragma unroll
      for (int t = 0; t < 9; ++t) {
        bf16x4 pk;
#pragma unroll
        for (int v = 0; v < 4; ++v) pk[v] = f2bf(sval[t][v]);
        const int byteoff = mloc * 288 + t * 32 + ich * 16 + g * 8;
        *(bf16x4*)(Ab + (byteoff ^ swzC)) = pk;
      }
    }
    __syncthreads();

    // ---- MFMA: 9 taps x (2 A-frags x 4 B-frags) ----
#pragma unroll
    for (int t = 0; t < 9; ++t) {
      const int j = t / 3, i = t % 3;
      bf16x8 A[2];
#pragma unroll
      for (int mf = 0; mf < 2; ++mf)
        A[mf] = *(const bf16x8*)(Ab + ((rawA[mf] + t * 32) ^ swzA[mf]));
      bf16x8 B[4];
#pragma unroll
      for (int nf = 0; nf < 4; ++nf) {
        const int ct = cellB[nf] + j * 34 + i;
        B[nf] = *(const bf16x8*)(xs + ct * 16 + q * 8);
      }
#pragma unroll
      for (int mf = 0; mf < 2; ++mf)
#pragma unroll
        for (int nf = 0; nf < 4; ++nf)
          acc[mf][nf] = __builtin_amdgcn_mfma_f32_32x32x16_bf16(A[mf], B[nf], acc[mf][nf], 0, 0, 0);
    }
  }

  // ---- epilogue: regs e = par (e&3), oc_local = 2*(e>>2)+q -> dense 2x2 quads ----
#pragma unroll
  for (int mf = 0; mf < 2; ++mf)
#pragma unroll
    for (int nf = 0; nf < 4; ++nf) {
      const int c = waveN * 128 + nf * 32 + l31;
      const int ay = c >> 5, bx = c & 31;
      const int arow = a0 + ay, bcol = b0 + bx;
#pragma unroll
      for (int r2 = 0; r2 < 4; ++r2) {
        const int oc = mtile * 32 + waveM * 16 + mf * 8 + 2 * r2 + q;
        float* op = out + (((size_t)(n * 256 + oc)) * 128 + 2 * arow) * 128 + 2 * bcol;
        f32x2 v0, v1;
        v0[0] = acc[mf][nf][4*r2+0]; v0[1] = acc[mf][nf][4*r2+1];  // row 2a, rx=0/1
        v1[0] = acc[mf][nf][4*r2+2]; v1[1] = acc[mf][nf][4*r2+3];  // row 2a+1
        *(f32x2*)op = v0;
        *(f32x2*)(op + 128) = v1;
      }
    }
}

extern "C" void kernel_launch(void* const* d_in, const int* in_sizes, int n_in,
                              void* d_out, int out_size, void* d_ws, size_t ws_size,
                              hipStream_t stream) {
  (void)in_sizes; (void)n_in; (void)out_size; (void)d_ws; (void)ws_size;
  const float* x = (const float*)d_in[0];
  const float* w = (const float*)d_in[1];
  float* out = (float*)d_out;
  // grid = 8 mtiles x 64 ntiles = 512 blocks
  hipLaunchKernelGGL(fir_up_v4, dim3(512), dim3(256), 0, stream, x, w, out);
}

// Round 6
// 106.023 us; speedup vs baseline: 20.3313x; 1.0774x over previous
//
#include <hip/hip_runtime.h>

// FirUpsample R5: FLOP-optimal two-stage form.
//   Stage 1 (MFMA): h = dilated conv3x3(x, w) computed as 4 parity-plane GEMMs:
//     h[2a'+py, 2b'+px] = sum_{ic} sum_{ky=py mod 2, kx=px mod 2}
//         w[oc,ic,ky,kx] * x[ic][a' + dy(ky,py), b' + dx(kx,px)]
//     K-depth per plane: (py,px)=(0,0):4 taps, (0,1):2, (1,0):2, (1,1):1 (x256 ic)
//     => 10.3 G MAC total vs 38.7 G for the parity-expanded composite GEMM.
//   Stage 2 (VALU): out[Y,X] = sum_{u,v} kf[u]kf[v] h[Y+2-u, X+2-v], kf={.25,.75,.75,.25}
//     h pad (h[-1], h[129]) is automatically 0 because x is zero-extended.
// One kernel, no global intermediate (graph-safe). h staged per block in LDS (bf16).
// Block: 512 thr (8 waves), M=64 oc, coarse tile 8x16 (out fine 16x32).

typedef short bf16x8 __attribute__((ext_vector_type(8)));
typedef short short4v __attribute__((ext_vector_type(4)));
typedef float f32x16 __attribute__((ext_vector_type(16)));
typedef float f32x4v __attribute__((ext_vector_type(4)));

static __device__ __forceinline__ short f2bf(float f) {
  union { float f; unsigned u; } v; v.f = f;
  unsigned r = (v.u + 0x7FFFu + ((v.u >> 16) & 1u)) >> 16;
  return (short)r;
}
static __device__ __forceinline__ float bf2f(short s) {
  union { unsigned u; float f; } v; v.u = ((unsigned)(unsigned short)s) << 16;
  return v.f;
}

__global__ __launch_bounds__(512)
void fir_up_v5(const float* __restrict__ x, const float* __restrict__ w,
               float* __restrict__ out) {
  // XCD swizzle: xcd = bid&7; octile-major so each XCD pair shares a w-slice.
  const int bid = blockIdx.x;
  const int wg = (bid & 7) * 64 + (bid >> 3);
  const int octile = wg >> 7;        // 0..3 (64 oc each)
  const int n = (wg >> 5) & 3;
  const int sp = wg & 31;
  const int atile = sp >> 2;         // 0..7 coarse-row tiles (8 rows each)
  const int btile = sp & 3;          // 0..3 coarse-col tiles (16 cols each)
  const int A0 = atile * 8, B0 = btile * 16;

  const int tid = threadIdx.x;
  const int wid = tid >> 6;
  const int lane = tid & 63;
  const int l31 = lane & 31, q = lane >> 5;

  __shared__ short As[9 * 64 * 16];       // [kq][oc64][ic16]  18.4 KB
  __shared__ short xs[180 * 16];          // [cell=r*18+c][ic16] 5.76 KB
  __shared__ short hl[4 * 32 * 10 * 20];  // [plane][ocl][r][c(pad 20)] 51.2 KB

  // plane geometry: p = py*2+px ; rows: even 9 odd 10 ; cols: even 17 odd 18
  const int COLSt[4]  = {17, 18, 17, 18};
  const int CELLSt[4] = {153, 162, 170, 180};
  const int NKt[4]    = {4, 2, 2, 1};
  const int KQt[4][4] = {{0,2,6,8},{1,7,7,7},{3,5,5,5},{4,4,4,4}};
  const int DYt[4][4] = {{0,0,1,1},{0,1,1,1},{0,0,0,0},{0,0,0,0}};
  const int DXt[4][4] = {{0,1,0,1},{0,0,0,0},{0,1,1,1},{0,0,0,0}};

  // per-wave frag assignment (8 waves x 3 slots), K-balanced (7,7,7,7,7,7,6,6):
  // w0:{p0#0,p1#0,p3#0} w1:{p0#1,p1#1,p3#1} w2:{p0#2,p1#2,p3#2}
  // w3:{p0#3,p2#0,p3#3} w4:{p0#4,p2#1,p3#4} w5:{p0#5(dummy),p2#2,p3#5}
  // w6:{p1#3,p1#4,p1#5} w7:{p2#3,p2#4,p2#5}
  const unsigned long long PLbits =
      (0x34ULL) | (0x34ULL << 6) | (0x34ULL << 12) | (0x38ULL << 18) |
      (0x38ULL << 24) | (0x38ULL << 30) | (0x15ULL << 36) | (0x2AULL << 42);
  const unsigned FG0 = 0u | 1u<<3 | 2u<<6 | 3u<<9 | 4u<<12 | 5u<<15 | 3u<<18 | 3u<<21;
  const unsigned FG1 = 0u | 1u<<3 | 2u<<6 | 0u<<9 | 1u<<12 | 2u<<15 | 4u<<18 | 4u<<21;
  const unsigned FG2 = 0u | 1u<<3 | 2u<<6 | 3u<<9 | 4u<<12 | 5u<<15 | 5u<<18 | 5u<<21;

  int nkS[3], validS[3], hbaseS[3];
  int kqS[3][4], cellxS[3][4];
#pragma unroll
  for (int slot = 0; slot < 3; ++slot) {
    const int p = (int)((PLbits >> ((wid * 3 + slot) * 2)) & 3ULL);
    const unsigned fgw = slot == 0 ? FG0 : (slot == 1 ? FG1 : FG2);
    const int fg = (int)((fgw >> (3 * wid)) & 7u);
    const int cellraw = fg * 32 + l31;
    const int valid = cellraw < CELLSt[p];
    const int cell = valid ? cellraw : 0;
    const int cols = COLSt[p];
    const int r = cell / cols;
    const int c = cell - r * cols;
    nkS[slot] = NKt[p];
    validS[slot] = valid;
    hbaseS[slot] = p * 6400 + r * 20 + c;
#pragma unroll
    for (int s = 0; s < 4; ++s) {
      kqS[slot][s] = KQt[p][s];
      cellxS[slot][s] = (r + DYt[p][s]) * 18 + (c + DXt[p][s]);
    }
  }

  f32x16 acc[3][2];
#pragma unroll
  for (int slot = 0; slot < 3; ++slot)
#pragma unroll
    for (int mf = 0; mf < 2; ++mf)
#pragma unroll
      for (int e = 0; e < 16; ++e) acc[slot][mf][e] = 0.f;

  // ---------------- K-loop: 16 chunks of 16 ic ----------------
  for (int cc = 0; cc < 16; ++cc) {
    __syncthreads();
    // stage x tile: rows [A0-1, A0+8], cols [B0-1, B0+16] -> 10x18 cells x 16 ic
    if (tid < 360) {
      const int cell = tid >> 1, half = tid & 1;
      const int hh = cell / 18, ww = cell - hh * 18;
      const int gh = A0 - 1 + hh, gw = B0 - 1 + ww;
      const bool ok = (gh >= 0) & (gh < 64) & (gw >= 0) & (gw < 64);
      const float* xp = x + (((size_t)(n * 256 + cc * 16 + half * 8)) * 64 + gh) * 64 + gw;
      bf16x8 vv;
#pragma unroll
      for (int e = 0; e < 8; ++e) {
        const float f = ok ? xp[(size_t)e * 4096] : 0.f;
        vv[e] = f2bf(f);
      }
      *(bf16x8*)(xs + cell * 16 + half * 8) = vv;
    }
    // stage A (= w bf16, no composition): 1024 units (oc64 x ic16)
#pragma unroll
    for (int t2 = 0; t2 < 2; ++t2) {
      const int u = tid + t2 * 512;
      const int ic = u & 15, oc = u >> 4;
      const float* wp = w + ((size_t)(octile * 64 + oc) * 256 + cc * 16 + ic) * 9;
#pragma unroll
      for (int kq = 0; kq < 9; ++kq)
        As[kq * 1024 + oc * 16 + ic] = f2bf(wp[kq]);
    }
    __syncthreads();

    // MFMA: per wave, its 3 slots; per slot, nk K-steps (one kq x 16 ic each)
#pragma unroll
    for (int slot = 0; slot < 3; ++slot) {
#pragma unroll
      for (int s = 0; s < 4; ++s) {
        if (s < nkS[slot]) {
          const int kq = kqS[slot][s];
          const bf16x8 B  = *(const bf16x8*)(xs + cellxS[slot][s] * 16 + q * 8);
          const bf16x8 Aa = *(const bf16x8*)(As + kq * 1024 + l31 * 16 + q * 8);
          const bf16x8 Ab = *(const bf16x8*)(As + kq * 1024 + (32 + l31) * 16 + q * 8);
          acc[slot][0] = __builtin_amdgcn_mfma_f32_32x32x16_bf16(Aa, B, acc[slot][0], 0, 0, 0);
          acc[slot][1] = __builtin_amdgcn_mfma_f32_32x32x16_bf16(Ab, B, acc[slot][1], 0, 0, 0);
        }
      }
    }
  }

  // ---------------- epilogue: 2 phases (mf = oc-half), h->LDS then 4x4 FIR ----------------
  const float kf4[4] = {0.25f, 0.75f, 0.75f, 0.25f};
#pragma unroll
  for (int mf = 0; mf < 2; ++mf) {
    __syncthreads();   // previous phase reads (or GEMM LDS reads) complete
    // write h (bf16): C-layout row = (e&3)+8*(e>>2)+4q = oc-local
#pragma unroll
    for (int slot = 0; slot < 3; ++slot) {
      if (validS[slot]) {
#pragma unroll
        for (int e = 0; e < 16; ++e) {
          const int ocl = (e & 3) + 8 * (e >> 2) + 4 * q;
          hl[hbaseS[slot] + ocl * 200] = f2bf(acc[slot][mf][e]);
        }
      }
    }
    __syncthreads();
    // FIR: 2048 units (ocl32 x Yl16 x g4), 4 per thread; lanes sweep (Yl,g) -> coalesced out
#pragma unroll
    for (int k = 0; k < 4; ++k) {
      const int v = tid + k * 512;
      const int g = v & 3;
      const int Yl = (v >> 2) & 15;
      const int ocl = v >> 6;
      float o[8];
#pragma unroll
      for (int xx = 0; xx < 8; ++xx) o[xx] = 0.f;
#pragma unroll
      for (int du = 0; du < 4; ++du) {
        const int ttp = Yl - 1 + du;          // local fine h-row minus 2A0
        const int py = ttp & 1;
        const int r = py ? ((Yl + du) >> 1) : (ttp >> 1);
        const int baseE = (py * 2) * 6400 + ocl * 200 + r * 20 + 4 * g;
        const int baseO = (py * 2 + 1) * 6400 + ocl * 200 + r * 20 + 4 * g;
        const short4v e0 = *(const short4v*)(hl + baseE);
        const short4v e1 = *(const short4v*)(hl + baseE + 4);
        const short4v o0 = *(const short4v*)(hl + baseO);
        const short4v o1 = *(const short4v*)(hl + baseO + 4);
        float E[8], O[8];
#pragma unroll
        for (int i = 0; i < 4; ++i) {
          E[i] = bf2f(e0[i]); E[i + 4] = bf2f(e1[i]);
          O[i] = bf2f(o0[i]); O[i + 4] = bf2f(o1[i]);
        }
        float rx[8];
        rx[0] = 0.25f*O[0] + 0.75f*E[0] + 0.75f*O[1] + 0.25f*E[1];
        rx[1] = 0.25f*E[0] + 0.75f*O[1] + 0.75f*E[1] + 0.25f*O[2];
        rx[2] = 0.25f*O[1] + 0.75f*E[1] + 0.75f*O[2] + 0.25f*E[2];
        rx[3] = 0.25f*E[1] + 0.75f*O[2] + 0.75f*E[2] + 0.25f*O[3];
        rx[4] = 0.25f*O[2] + 0.75f*E[2] + 0.75f*O[3] + 0.25f*E[3];
        rx[5] = 0.25f*E[2] + 0.75f*O[3] + 0.75f*E[3] + 0.25f*O[4];
        rx[6] = 0.25f*O[3] + 0.75f*E[3] + 0.75f*O[4] + 0.25f*E[4];
        rx[7] = 0.25f*E[3] + 0.75f*O[4] + 0.75f*E[4] + 0.25f*O[5];
        const float ky = kf4[du];
#pragma unroll
        for (int xx = 0; xx < 8; ++xx) o[xx] += ky * rx[xx];
      }
      const int oc = octile * 64 + mf * 32 + ocl;
      const int Y = atile * 16 + Yl;
      const int X0 = btile * 32 + g * 8;
      float* op = out + (((size_t)(n * 256 + oc)) * 128 + Y) * 128 + X0;
      f32x4v v0, v1;
      v0[0] = o[0]; v0[1] = o[1]; v0[2] = o[2]; v0[3] = o[3];
      v1[0] = o[4]; v1[1] = o[5]; v1[2] = o[6]; v1[3] = o[7];
      *(f32x4v*)op = v0;
      *(f32x4v*)(op + 4) = v1;
    }
  }
}

extern "C" void kernel_launch(void* const* d_in, const int* in_sizes, int n_in,
                              void* d_out, int out_size, void* d_ws, size_t ws_size,
                              hipStream_t stream) {
  (void)in_sizes; (void)n_in; (void)out_size; (void)d_ws; (void)ws_size;
  const float* x = (const float*)d_in[0];
  const float* w = (const float*)d_in[1];
  float* out = (float*)d_out;
  // grid = 4 octiles x 4 n x 32 spatial = 512 blocks, 512 threads (8 waves)
  hipLaunchKernelGGL(fir_up_v5, dim3(512), dim3(512), 0, stream, x, w, out);
}